// Round 5
// baseline (862.487 us; speedup 1.0000x reference)
//
#include <hip/hip_runtime.h>
#include <math.h>

// Transformer block fwd: B=16, N=1024, D=768, H=12, HD=64, MLP=3072.
// Round 5: bf16-MFMA GEMMs (m97-style, unchanged from audited round-4) +
// NEW bf16-MFMA flash attention (16x16x32, XOR-swizzled LDS, wave-private P).
// Rounds 0-4 never ran (GPU acquisition timeouts).
// Fallback ladder if validation fails:
//   absmax ~1e-2 -> tolerance: revert GEMMs+attn to fp32 (round-1 source).
//   absmax ~O(1) -> layout bug: first revert attn to fp32 (round-4 source)
//                   to isolate GEMM vs attn; then audit vs m89 maps.

#define BS   16
#define SEQ  1024
#define DIM  768
#define NH   12
#define HDM  64
#define MLPD 3072
#define NTOK (BS * SEQ)          // 16384

typedef unsigned short u16;
typedef __attribute__((ext_vector_type(8))) short bf16x8;  // 8 bf16 (4 VGPRs)
typedef __attribute__((ext_vector_type(4))) float f32x4;   // MFMA acc

__device__ __forceinline__ float gelu_exact(float x) {
  return 0.5f * x * (1.0f + erff(x * 0.70710678118654752440f));
}
__device__ __forceinline__ u16 f2bf(float f) {  // RTNE, matches HW convert
  unsigned u = __float_as_uint(f);
  return (u16)((u + 0x7fffu + ((u >> 16) & 1u)) >> 16);
}
__device__ __forceinline__ float bf2f(u16 h) {
  return __uint_as_float((unsigned)h << 16);
}

// ---------------------------------------------------------------------------
// Weight convert+transpose: fp32 W[K][N] -> bf16 Wt[N][K]. 64x64 LDS tile.
// ---------------------------------------------------------------------------
__global__ __launch_bounds__(256) void wtrans_kernel(
    const float* __restrict__ W, u16* __restrict__ Wt, int K, int N) {
  __shared__ u16 t[64][65];
  const int k0 = blockIdx.y << 6, n0 = blockIdx.x << 6;
  const int r  = threadIdx.x >> 2;            // 0..63
  const int c4 = (threadIdx.x & 3) << 4;      // 0,16,32,48
#pragma unroll
  for (int c = 0; c < 16; c += 4) {
    const float4 v = *(const float4*)(W + (size_t)(k0 + r) * N + n0 + c4 + c);
    t[r][c4 + c + 0] = f2bf(v.x);
    t[r][c4 + c + 1] = f2bf(v.y);
    t[r][c4 + c + 2] = f2bf(v.z);
    t[r][c4 + c + 3] = f2bf(v.w);
  }
  __syncthreads();
  unsigned wbuf[8];
#pragma unroll
  for (int p = 0; p < 8; ++p)
    wbuf[p] = (unsigned)t[c4 + 2 * p][r] | ((unsigned)t[c4 + 2 * p + 1][r] << 16);
  uint4* dst = (uint4*)(Wt + (size_t)(n0 + r) * K + k0 + c4);
  dst[0] = make_uint4(wbuf[0], wbuf[1], wbuf[2], wbuf[3]);
  dst[1] = make_uint4(wbuf[4], wbuf[5], wbuf[6], wbuf[7]);
}

// ---------------------------------------------------------------------------
// LayerNorm (fp32 in, bf16 out): one wave per token, 4 tokens per block.
// ---------------------------------------------------------------------------
__global__ __launch_bounds__(256) void ln_kernel(
    const float* __restrict__ x, const float* __restrict__ g,
    const float* __restrict__ b, u16* __restrict__ out) {
  const int lane = threadIdx.x & 63;
  const int wv   = threadIdx.x >> 6;
  const int tok  = (blockIdx.x << 2) + wv;
  const float4* xr = (const float4*)(x + (size_t)tok * DIM);
  float4 a0 = xr[lane], a1 = xr[lane + 64], a2 = xr[lane + 128];
  float s  = a0.x + a0.y + a0.z + a0.w + a1.x + a1.y + a1.z + a1.w
           + a2.x + a2.y + a2.z + a2.w;
  float s2 = a0.x*a0.x + a0.y*a0.y + a0.z*a0.z + a0.w*a0.w
           + a1.x*a1.x + a1.y*a1.y + a1.z*a1.z + a1.w*a1.w
           + a2.x*a2.x + a2.y*a2.y + a2.z*a2.z + a2.w*a2.w;
#pragma unroll
  for (int o = 32; o; o >>= 1) {
    s  += __shfl_xor(s,  o, 64);
    s2 += __shfl_xor(s2, o, 64);
  }
  const float mu   = s * (1.0f / DIM);
  const float rstd = rsqrtf(s2 * (1.0f / DIM) - mu * mu + 1e-6f);
  const float4* gp = (const float4*)g;
  const float4* bp = (const float4*)b;
  ushort4* op = (ushort4*)(out + (size_t)tok * DIM);
#define LN_EMIT(av, idx)                                                       \
  {                                                                            \
    const float4 gv = gp[idx]; const float4 bv = bp[idx]; ushort4 ov;          \
    ov.x = f2bf((av.x - mu) * rstd * gv.x + bv.x);                             \
    ov.y = f2bf((av.y - mu) * rstd * gv.y + bv.y);                             \
    ov.z = f2bf((av.z - mu) * rstd * gv.z + bv.z);                             \
    ov.w = f2bf((av.w - mu) * rstd * gv.w + bv.w);                             \
    op[idx] = ov;                                                              \
  }
  LN_EMIT(a0, lane);
  LN_EMIT(a1, lane + 64);
  LN_EMIT(a2, lane + 128);
#undef LN_EMIT
}

// ---------------------------------------------------------------------------
// bf16 MFMA GEMM (unchanged from audited round-4). 128x128 tile, BK=32,
// 4 waves 2x2, 4x4 16x16x32 fragments/wave, dbuf LDS, global_load_lds w=16.
// Fragment maps: A[l&15][(l>>4)*8+j]; B[(l>>4)*8+j][l&15];
// C/D col=l&15, row=(l>>4)*4+reg  [m89/m91-verified].
// EPI: 0 bias; 1 bias+res(fp32); 2 bias+GELU.  OUTBF: 1 -> bf16 out.
// ---------------------------------------------------------------------------
__device__ __forceinline__ void stage128x32(const u16* gtile, int ldk,
                                            u16* lds, int tid) {
#pragma unroll
  for (int i = 0; i < 2; ++i) {
    const int b = i * 4096 + tid * 16;     // byte offset within tile
    const int row = b >> 6;
    const int chunk = (b >> 4) & 3;
    const u16* src = gtile + (size_t)row * ldk + chunk * 8;
    u16* dst = lds + ((i * 4096 + (tid >> 6) * 1024) >> 1);  // wave-uniform
    __builtin_amdgcn_global_load_lds((const void*)src, (void*)dst, 16, 0, 0);
  }
}

template <int EPI, int OUTBF>
__global__ __launch_bounds__(256) void mm_kernel(
    const u16* __restrict__ A, const u16* __restrict__ Wt,
    const float* __restrict__ bias, const float* res, void* outp,
    int M, int K, int Nc) {
  __shared__ __align__(16) u16 As[2][128 * 32];
  __shared__ __align__(16) u16 Bs[2][128 * 32];
  const int tid  = threadIdx.x;
  const int lane = tid & 63;
  const int wid  = tid >> 6;
  const int wr   = (wid >> 1) << 6;
  const int wc   = (wid & 1) << 6;
  const int row0 = blockIdx.y << 7;
  const int col0 = blockIdx.x << 7;
  const int fr   = lane & 15;
  const int kch  = lane >> 4;
  const u16* Ab = A  + (size_t)row0 * K;
  const u16* Bb = Wt + (size_t)col0 * K;
  const int nkt = K >> 5;

  f32x4 acc[4][4];
#pragma unroll
  for (int i = 0; i < 4; ++i)
#pragma unroll
    for (int j = 0; j < 4; ++j) acc[i][j] = {0.f, 0.f, 0.f, 0.f};

  stage128x32(Ab, K, As[0], tid);
  stage128x32(Bb, K, Bs[0], tid);
  __syncthreads();

  int cur = 0;
  for (int kt = 0; kt < nkt; ++kt) {
    if (kt + 1 < nkt) {
      stage128x32(Ab + (kt + 1) * 32, K, As[cur ^ 1], tid);
      stage128x32(Bb + (kt + 1) * 32, K, Bs[cur ^ 1], tid);
    }
    bf16x8 af[4], bf[4];
#pragma unroll
    for (int f = 0; f < 4; ++f) {
      af[f] = *(const bf16x8*)&As[cur][(wr + (f << 4) + fr) * 32 + (kch << 3)];
      bf[f] = *(const bf16x8*)&Bs[cur][(wc + (f << 4) + fr) * 32 + (kch << 3)];
    }
#pragma unroll
    for (int i = 0; i < 4; ++i)
#pragma unroll
      for (int j = 0; j < 4; ++j)
        acc[i][j] = __builtin_amdgcn_mfma_f32_16x16x32_bf16(af[i], bf[j],
                                                            acc[i][j], 0, 0, 0);
    __syncthreads();
    cur ^= 1;
  }

  float* outf = (float*)outp;
  u16*   outb = (u16*)outp;
#pragma unroll
  for (int jf = 0; jf < 4; ++jf) {
    const int c = col0 + wc + (jf << 4) + fr;
    const float bv = bias[c];
#pragma unroll
    for (int i = 0; i < 4; ++i) {
#pragma unroll
      for (int j = 0; j < 4; ++j) {
        const int r = row0 + wr + (i << 4) + ((lane >> 4) << 2) + j;
        float v = acc[i][jf][j] + bv;
        if (EPI == 1) v += res[(size_t)r * Nc + c];
        if (EPI == 2) v = gelu_exact(v);
        if (OUTBF) outb[(size_t)r * Nc + c] = f2bf(v);
        else       outf[(size_t)r * Nc + c] = v;
      }
    }
  }
}

// ---------------------------------------------------------------------------
// bf16-MFMA flash attention. Block = (qtile 64 rows, head, batch); 4 waves,
// wave w owns q-strip rows [16w,16w+16). Per 64-wide K-tile:
//   S-strip(16x64) = Q.K^T via 8 mfma_16x16x32 (B-frag from row-major K!),
//   online softmax (reg-level, 16-lane shfl reduce), P->LDS bf16 (wave-
//   private strip, no barrier), ctx-strip += P.V via 8 MFMA with V staged
//   TRANSPOSED (Vt[d][kcol]) so B-frags are b128.
// All LDS buffers [64][64] bf16 (128B row stride -> 16-way conflict if
// linear) accessed through XOR swizzle chunk^=row&7 on BOTH write and read.
// LDS 32KB, 2 barriers/tile.
// ---------------------------------------------------------------------------
__device__ __forceinline__ int swz(int row, int chunk) {  // byte offset
  return row * 128 + ((chunk ^ (row & 7)) << 4);
}

__global__ __launch_bounds__(256) void attn_kernel(
    const u16* __restrict__ q, const u16* __restrict__ k,
    const u16* __restrict__ v, u16* __restrict__ ctx) {
  __shared__ __align__(16) u16 Qs[4096];   // [qrow][d]   swz
  __shared__ __align__(16) u16 Ks[4096];   // [kcol][d]   swz
  __shared__ __align__(16) u16 Vt[4096];   // [d][kcol]   swz (transposed)
  __shared__ __align__(16) u16 Ps[4096];   // [qrow][kcol] swz, wave-private strips
  const int tid  = threadIdx.x;
  const int lane = tid & 63;
  const int w    = tid >> 6;          // wave id -> q-strip base 16w
  const int fr   = lane & 15;         // fragment row index
  const int g    = lane >> 4;         // k-chunk group 0..3
  const int qt = blockIdx.x, h = blockIdx.y, b = blockIdx.z;
  const size_t hbase = (size_t)b * SEQ * DIM + (size_t)h * HDM;
  const int srow = tid >> 2;          // staging row 0..63
  const int sc   = (tid & 3) << 4;    // staging col 0,16,32,48
  const int sch  = sc >> 3;           // staging chunk base (0,2,4,6)

  {  // stage Q strip (rows = this wave's own strip; barrier B covers anyway)
    const u16* qp = q + hbase + (size_t)(qt * 64 + srow) * DIM + sc;
    const uint4 q0 = *(const uint4*)qp;
    const uint4 q1 = *(const uint4*)(qp + 8);
    *(uint4*)((char*)Qs + swz(srow, sch))     = q0;
    *(uint4*)((char*)Qs + swz(srow, sch + 1)) = q1;
  }

  float m_[4] = {-INFINITY, -INFINITY, -INFINITY, -INFINITY};
  float l_[4] = {0.f, 0.f, 0.f, 0.f};
  f32x4 oacc[4];  // ctx accum: frag f -> d=f*16+fr, reg r -> qrow g*4+r
#pragma unroll
  for (int f = 0; f < 4; ++f) oacc[f] = {0.f, 0.f, 0.f, 0.f};

  for (int kt = 0; kt < SEQ / 64; ++kt) {
    __syncthreads();  // prior tile's K/Vt reads complete
    {  // stage K tile [kcol][d]
      const u16* kp = k + hbase + (size_t)(kt * 64 + srow) * DIM + sc;
      const uint4 k0 = *(const uint4*)kp;
      const uint4 k1 = *(const uint4*)(kp + 8);
      *(uint4*)((char*)Ks + swz(srow, sch))     = k0;
      *(uint4*)((char*)Ks + swz(srow, sch + 1)) = k1;
      // stage V transposed: this thread covers kcol=srow, d in [sc, sc+16)
      const u16* vp = v + hbase + (size_t)(kt * 64 + srow) * DIM + sc;
      const uint4 v0 = *(const uint4*)vp;
      const uint4 v1 = *(const uint4*)(vp + 8);
      const unsigned uw[8] = {v0.x, v0.y, v0.z, v0.w, v1.x, v1.y, v1.z, v1.w};
#pragma unroll
      for (int e = 0; e < 16; ++e) {
        const u16 val = (e & 1) ? (u16)(uw[e >> 1] >> 16)
                                : (u16)(uw[e >> 1] & 0xffffu);
        const int d = sc + e;
        *(u16*)((char*)Vt + ((d * 128 + srow * 2) ^ ((d & 7) << 4))) = val;
      }
    }
    __syncthreads();  // K/Vt ready

    // ---- S-strip = Q.K^T : A=Q[w*16+fr][s*32+g*8+j], B-frag from K rows ----
    f32x4 sacc[4];
#pragma unroll
    for (int f = 0; f < 4; ++f) sacc[f] = {0.f, 0.f, 0.f, 0.f};
    bf16x8 aq[2];
#pragma unroll
    for (int s = 0; s < 2; ++s)
      aq[s] = *(const bf16x8*)((char*)Qs + swz(w * 16 + fr, s * 4 + g));
#pragma unroll
    for (int f = 0; f < 4; ++f)
#pragma unroll
      for (int s = 0; s < 2; ++s) {
        const bf16x8 bk =
            *(const bf16x8*)((char*)Ks + swz(f * 16 + fr, s * 4 + g));
        sacc[f] = __builtin_amdgcn_mfma_f32_16x16x32_bf16(aq[s], bk, sacc[f],
                                                          0, 0, 0);
      }

    // ---- online softmax; row r of strip held at reg r across 16 fr-lanes --
    float corr[4];
#pragma unroll
    for (int r = 0; r < 4; ++r) {
#pragma unroll
      for (int f = 0; f < 4; ++f) sacc[f][r] *= 0.125f;  // 1/sqrt(64)
      float rm = fmaxf(fmaxf(sacc[0][r], sacc[1][r]),
                       fmaxf(sacc[2][r], sacc[3][r]));
#pragma unroll
      for (int o = 8; o; o >>= 1) rm = fmaxf(rm, __shfl_xor(rm, o, 64));
      const float mnew = fmaxf(m_[r], rm);
      corr[r] = expf(m_[r] - mnew);  // first tile: exp(-inf)=0
      float ps = 0.f;
#pragma unroll
      for (int f = 0; f < 4; ++f) {
        const float p = expf(sacc[f][r] - mnew);
        sacc[f][r] = p;
        ps += p;
      }
#pragma unroll
      for (int o = 8; o; o >>= 1) ps += __shfl_xor(ps, o, 64);
      l_[r] = l_[r] * corr[r] + ps;
      m_[r] = mnew;
#pragma unroll
      for (int f = 0; f < 4; ++f) oacc[f][r] *= corr[r];
    }

    // ---- P -> LDS bf16 (wave-private strip: rows 16w..16w+15) ----
#pragma unroll
    for (int f = 0; f < 4; ++f)
#pragma unroll
      for (int r = 0; r < 4; ++r) {
        const int row = w * 16 + g * 4 + r;
        const int col = f * 16 + fr;
        *(u16*)((char*)Ps + ((row * 128 + col * 2) ^ ((row & 7) << 4))) =
            f2bf(sacc[f][r]);
      }
    // same-wave ds_write -> ds_read on same array: compiler orders via lgkmcnt

    // ---- ctx-strip += P.V : A=P[w*16+fr][...], B-frag from Vt rows ----
    bf16x8 ap[2];
#pragma unroll
    for (int s = 0; s < 2; ++s)
      ap[s] = *(const bf16x8*)((char*)Ps + swz(w * 16 + fr, s * 4 + g));
#pragma unroll
    for (int f = 0; f < 4; ++f)
#pragma unroll
      for (int s = 0; s < 2; ++s) {
        const bf16x8 bv =
            *(const bf16x8*)((char*)Vt + swz(f * 16 + fr, s * 4 + g));
        oacc[f] = __builtin_amdgcn_mfma_f32_16x16x32_bf16(ap[s], bv, oacc[f],
                                                          0, 0, 0);
      }
  }

  // epilogue: ctx[qrow=w*16+g*4+r][d=f*16+fr] = oacc[f][r]/l_[r]
  float inv[4];
#pragma unroll
  for (int r = 0; r < 4; ++r) inv[r] = 1.0f / l_[r];
#pragma unroll
  for (int f = 0; f < 4; ++f)
#pragma unroll
    for (int r = 0; r < 4; ++r) {
      const int qrow = qt * 64 + w * 16 + g * 4 + r;
      ctx[hbase + (size_t)qrow * DIM + f * 16 + fr] = f2bf(oacc[f][r] * inv[r]);
    }
}

// ---------------------------------------------------------------------------
// Orchestration. ws (bf16 elems): Wt x6 (7.08M) | tokb (TD: h->ctx->h2) |
// qkv (3*TD; reused+extended as MLP act 4*TD). Total 70.0M u16 = 140 MB.
// ---------------------------------------------------------------------------
extern "C" void kernel_launch(void* const* d_in, const int* in_sizes, int n_in,
                              void* d_out, int out_size, void* d_ws,
                              size_t ws_size, hipStream_t stream) {
  const float* x    = (const float*)d_in[0];
  const float* wq   = (const float*)d_in[1];
  const float* bq   = (const float*)d_in[2];
  const float* wk   = (const float*)d_in[3];
  const float* bk   = (const float*)d_in[4];
  const float* wv   = (const float*)d_in[5];
  const float* bv   = (const float*)d_in[6];
  const float* wo   = (const float*)d_in[7];
  const float* bo   = (const float*)d_in[8];
  const float* w1   = (const float*)d_in[9];
  const float* b1   = (const float*)d_in[10];
  const float* w2   = (const float*)d_in[11];
  const float* b2   = (const float*)d_in[12];
  const float* ln1g = (const float*)d_in[13];
  const float* ln1b = (const float*)d_in[14];
  const float* ln2g = (const float*)d_in[15];
  const float* ln2b = (const float*)d_in[16];
  float* out = (float*)d_out;

  const size_t TD = (size_t)NTOK * DIM;     // 12.58M
  const size_t S768 = (size_t)DIM * DIM;    // 589824
  const size_t SMLP = (size_t)DIM * MLPD;   // 2359296
  u16* wtq  = (u16*)d_ws;
  u16* wtk  = wtq + S768;
  u16* wtv  = wtk + S768;
  u16* wto  = wtv + S768;
  u16* wt1  = wto + S768;                   // [MLPD][DIM]
  u16* wt2  = wt1 + SMLP;                   // [DIM][MLPD]
  u16* tokb = wt2 + SMLP;                   // h -> ctx -> h2
  u16* qb   = tokb + TD;                    // q; later MLP act (4*TD)
  u16* kb   = qb + TD;
  u16* vb   = kb + TD;

  const dim3 blk(256);
  wtrans_kernel<<<dim3(DIM / 64, DIM / 64), blk, 0, stream>>>(wq, wtq, DIM, DIM);
  wtrans_kernel<<<dim3(DIM / 64, DIM / 64), blk, 0, stream>>>(wk, wtk, DIM, DIM);
  wtrans_kernel<<<dim3(DIM / 64, DIM / 64), blk, 0, stream>>>(wv, wtv, DIM, DIM);
  wtrans_kernel<<<dim3(DIM / 64, DIM / 64), blk, 0, stream>>>(wo, wto, DIM, DIM);
  wtrans_kernel<<<dim3(MLPD / 64, DIM / 64), blk, 0, stream>>>(w1, wt1, DIM, MLPD);
  wtrans_kernel<<<dim3(DIM / 64, MLPD / 64), blk, 0, stream>>>(w2, wt2, MLPD, DIM);
  ln_kernel<<<dim3(NTOK / 4), blk, 0, stream>>>(x, ln1g, ln1b, tokb);
  const dim3 g768(DIM / 128, NTOK / 128);   // (6,128)
  mm_kernel<0, 1><<<g768, blk, 0, stream>>>(tokb, wtq, bq, nullptr, qb, NTOK, DIM, DIM);
  mm_kernel<0, 1><<<g768, blk, 0, stream>>>(tokb, wtk, bk, nullptr, kb, NTOK, DIM, DIM);
  mm_kernel<0, 1><<<g768, blk, 0, stream>>>(tokb, wtv, bv, nullptr, vb, NTOK, DIM, DIM);
  attn_kernel<<<dim3(SEQ / 64, NH, BS), blk, 0, stream>>>(qb, kb, vb, tokb);
  mm_kernel<1, 0><<<g768, blk, 0, stream>>>(tokb, wto, bo, x, out, NTOK, DIM, DIM);
  ln_kernel<<<dim3(NTOK / 4), blk, 0, stream>>>(out, ln2g, ln2b, tokb);
  mm_kernel<2, 1><<<dim3(MLPD / 128, NTOK / 128), blk, 0, stream>>>(
      tokb, wt1, b1, nullptr, qb, NTOK, DIM, MLPD);
  mm_kernel<1, 0><<<g768, blk, 0, stream>>>(qb, wt2, b2, out, out, NTOK, MLPD, DIM);
}

// Round 7
// 796.721 us; speedup vs baseline: 1.0825x; 1.0825x over previous
//
#include <hip/hip_runtime.h>
#include <hip/hip_bf16.h>
#include <math.h>

// Transformer block fwd: B=16, N=1024, D=768, H=12, HD=64, MLP=3072.
// Round 7 resubmit (re-audited, unchanged from R6): attn VALU-cut.
// R5 PASSED (862us, absmax 0.03125): attn 258us was VALU-bound (MfmaUtil
// 8.6%, VALUBusy 67%) on scalar V-transpose + scalar f2bf/expf. Changes vs
// R5: V-GEMM writes vt[b][h][d][n] directly (kills attn's in-LDS V
// transpose), Q prescaled 0.125 in Q-GEMM epilogue, __expf, HW bf16
// converts. mm structure (m97-style) unchanged.

#define BS   16
#define SEQ  1024
#define DIM  768
#define NH   12
#define HDM  64
#define MLPD 3072
#define NTOK (BS * SEQ)          // 16384

typedef unsigned short u16;
typedef __attribute__((ext_vector_type(8))) short bf16x8;  // 8 bf16 (4 VGPRs)
typedef __attribute__((ext_vector_type(4))) float f32x4;   // MFMA acc

__device__ __forceinline__ float gelu_exact(float x) {
  return 0.5f * x * (1.0f + erff(x * 0.70710678118654752440f));
}
__device__ __forceinline__ u16 f2bf(float f) {  // HW convert (RTNE)
  __hip_bfloat16 h = __float2bfloat16(f);
  u16 r;
  __builtin_memcpy(&r, &h, 2);
  return r;
}
__device__ __forceinline__ u16 f2bf_sw(float f) {  // manual RTNE (cold paths)
  unsigned u = __float_as_uint(f);
  return (u16)((u + 0x7fffu + ((u >> 16) & 1u)) >> 16);
}

// ---------------------------------------------------------------------------
// Weight convert+transpose: fp32 W[K][N] -> bf16 Wt[N][K]. 64x64 LDS tile.
// ---------------------------------------------------------------------------
__global__ __launch_bounds__(256) void wtrans_kernel(
    const float* __restrict__ W, u16* __restrict__ Wt, int K, int N) {
  __shared__ u16 t[64][65];
  const int k0 = blockIdx.y << 6, n0 = blockIdx.x << 6;
  const int r  = threadIdx.x >> 2;            // 0..63
  const int c4 = (threadIdx.x & 3) << 4;      // 0,16,32,48
#pragma unroll
  for (int c = 0; c < 16; c += 4) {
    const float4 v = *(const float4*)(W + (size_t)(k0 + r) * N + n0 + c4 + c);
    t[r][c4 + c + 0] = f2bf_sw(v.x);
    t[r][c4 + c + 1] = f2bf_sw(v.y);
    t[r][c4 + c + 2] = f2bf_sw(v.z);
    t[r][c4 + c + 3] = f2bf_sw(v.w);
  }
  __syncthreads();
  unsigned wbuf[8];
#pragma unroll
  for (int p = 0; p < 8; ++p)
    wbuf[p] = (unsigned)t[c4 + 2 * p][r] | ((unsigned)t[c4 + 2 * p + 1][r] << 16);
  uint4* dst = (uint4*)(Wt + (size_t)(n0 + r) * K + k0 + c4);
  dst[0] = make_uint4(wbuf[0], wbuf[1], wbuf[2], wbuf[3]);
  dst[1] = make_uint4(wbuf[4], wbuf[5], wbuf[6], wbuf[7]);
}

// ---------------------------------------------------------------------------
// LayerNorm (fp32 in, bf16 out): one wave per token, 4 tokens per block.
// ---------------------------------------------------------------------------
__global__ __launch_bounds__(256) void ln_kernel(
    const float* __restrict__ x, const float* __restrict__ g,
    const float* __restrict__ b, u16* __restrict__ out) {
  const int lane = threadIdx.x & 63;
  const int wv   = threadIdx.x >> 6;
  const int tok  = (blockIdx.x << 2) + wv;
  const float4* xr = (const float4*)(x + (size_t)tok * DIM);
  float4 a0 = xr[lane], a1 = xr[lane + 64], a2 = xr[lane + 128];
  float s  = a0.x + a0.y + a0.z + a0.w + a1.x + a1.y + a1.z + a1.w
           + a2.x + a2.y + a2.z + a2.w;
  float s2 = a0.x*a0.x + a0.y*a0.y + a0.z*a0.z + a0.w*a0.w
           + a1.x*a1.x + a1.y*a1.y + a1.z*a1.z + a1.w*a1.w
           + a2.x*a2.x + a2.y*a2.y + a2.z*a2.z + a2.w*a2.w;
#pragma unroll
  for (int o = 32; o; o >>= 1) {
    s  += __shfl_xor(s,  o, 64);
    s2 += __shfl_xor(s2, o, 64);
  }
  const float mu   = s * (1.0f / DIM);
  const float rstd = rsqrtf(s2 * (1.0f / DIM) - mu * mu + 1e-6f);
  const float4* gp = (const float4*)g;
  const float4* bp = (const float4*)b;
  ushort4* op = (ushort4*)(out + (size_t)tok * DIM);
#define LN_EMIT(av, idx)                                                       \
  {                                                                            \
    const float4 gv = gp[idx]; const float4 bv = bp[idx]; ushort4 ov;          \
    ov.x = f2bf((av.x - mu) * rstd * gv.x + bv.x);                             \
    ov.y = f2bf((av.y - mu) * rstd * gv.y + bv.y);                             \
    ov.z = f2bf((av.z - mu) * rstd * gv.z + bv.z);                             \
    ov.w = f2bf((av.w - mu) * rstd * gv.w + bv.w);                             \
    op[idx] = ov;                                                              \
  }
  LN_EMIT(a0, lane);
  LN_EMIT(a1, lane + 64);
  LN_EMIT(a2, lane + 128);
#undef LN_EMIT
}

// ---------------------------------------------------------------------------
// bf16 MFMA GEMM (m97-style; structure unchanged from PASSED round-5).
// 128x128 tile, BK=32, 4 waves 2x2, dbuf LDS, global_load_lds w=16.
// Fragment maps [m89/m91-verified + R5 HW-PASS]:
//   A[l&15][(l>>4)*8+j]; B[(l>>4)*8+j][l&15]; C/D col=l&15, row=(l>>4)*4+reg.
// EPI: 0 bias->bf16 (K-proj)
//      1 bias+res(fp32)->fp32 (O-proj, MLP2)
//      2 bias+GELU->bf16 (MLP1)
//      3 bias, *0.125 ->bf16 (Q-proj; folds attn scale; 2^-3 exact)
//      4 bias -> vt[b][h][d][n] bf16 scatter (V-proj; kills attn V-transpose)
// ---------------------------------------------------------------------------
__device__ __forceinline__ void stage128x32(const u16* gtile, int ldk,
                                            u16* lds, int tid) {
#pragma unroll
  for (int i = 0; i < 2; ++i) {
    const int b = i * 4096 + tid * 16;     // byte offset within tile
    const int row = b >> 6;
    const int chunk = (b >> 4) & 3;
    const u16* src = gtile + (size_t)row * ldk + chunk * 8;
    u16* dst = lds + ((i * 4096 + (tid >> 6) * 1024) >> 1);  // wave-uniform
    __builtin_amdgcn_global_load_lds((const void*)src, (void*)dst, 16, 0, 0);
  }
}

template <int EPI>
__global__ __launch_bounds__(256) void mm_kernel(
    const u16* __restrict__ A, const u16* __restrict__ Wt,
    const float* __restrict__ bias, const float* res, void* outp,
    int M, int K, int Nc) {
  __shared__ __align__(16) u16 As[2][128 * 32];
  __shared__ __align__(16) u16 Bs[2][128 * 32];
  const int tid  = threadIdx.x;
  const int lane = tid & 63;
  const int wid  = tid >> 6;
  const int wr   = (wid >> 1) << 6;
  const int wc   = (wid & 1) << 6;
  const int row0 = blockIdx.y << 7;
  const int col0 = blockIdx.x << 7;
  const int fr   = lane & 15;
  const int kch  = lane >> 4;
  const u16* Ab = A  + (size_t)row0 * K;
  const u16* Bb = Wt + (size_t)col0 * K;
  const int nkt = K >> 5;

  f32x4 acc[4][4];
#pragma unroll
  for (int i = 0; i < 4; ++i)
#pragma unroll
    for (int j = 0; j < 4; ++j) acc[i][j] = {0.f, 0.f, 0.f, 0.f};

  stage128x32(Ab, K, As[0], tid);
  stage128x32(Bb, K, Bs[0], tid);
  __syncthreads();

  int cur = 0;
  for (int kt = 0; kt < nkt; ++kt) {
    if (kt + 1 < nkt) {
      stage128x32(Ab + (kt + 1) * 32, K, As[cur ^ 1], tid);
      stage128x32(Bb + (kt + 1) * 32, K, Bs[cur ^ 1], tid);
    }
    bf16x8 af[4], bf[4];
#pragma unroll
    for (int f = 0; f < 4; ++f) {
      af[f] = *(const bf16x8*)&As[cur][(wr + (f << 4) + fr) * 32 + (kch << 3)];
      bf[f] = *(const bf16x8*)&Bs[cur][(wc + (f << 4) + fr) * 32 + (kch << 3)];
    }
#pragma unroll
    for (int i = 0; i < 4; ++i)
#pragma unroll
      for (int j = 0; j < 4; ++j)
        acc[i][j] = __builtin_amdgcn_mfma_f32_16x16x32_bf16(af[i], bf[j],
                                                            acc[i][j], 0, 0, 0);
    __syncthreads();
    cur ^= 1;
  }

  float* outf = (float*)outp;
  u16*   outb = (u16*)outp;
#pragma unroll
  for (int jf = 0; jf < 4; ++jf) {
    const int c = col0 + wc + (jf << 4) + fr;
    const float bv = bias[c];
    if (EPI == 4) {
      const int hh = c >> 6, dd = c & 63;
#pragma unroll
      for (int i = 0; i < 4; ++i) {
        const int rbase = row0 + wr + (i << 4) + ((lane >> 4) << 2);
        const int bb = rbase >> 10, n0 = rbase & 1023;  // batch, seq-pos
        ushort4 o;
        o.x = f2bf(acc[i][jf][0] + bv);
        o.y = f2bf(acc[i][jf][1] + bv);
        o.z = f2bf(acc[i][jf][2] + bv);
        o.w = f2bf(acc[i][jf][3] + bv);
        *(ushort4*)(outb + ((((size_t)bb * NH + hh) * HDM + dd) << 10) + n0) = o;
      }
    } else {
#pragma unroll
      for (int i = 0; i < 4; ++i) {
#pragma unroll
        for (int j = 0; j < 4; ++j) {
          const int r = row0 + wr + (i << 4) + ((lane >> 4) << 2) + j;
          float v = acc[i][jf][j] + bv;
          if (EPI == 1) v += res[(size_t)r * Nc + c];
          if (EPI == 2) v = gelu_exact(v);
          if (EPI == 3) v *= 0.125f;
          if (EPI == 1) outf[(size_t)r * Nc + c] = v;
          else          outb[(size_t)r * Nc + c] = f2bf(v);
        }
      }
    }
  }
}

// ---------------------------------------------------------------------------
// bf16-MFMA flash attention (structure HW-validated in R5). Block = (qtile
// 64 rows, head, batch); 4 waves, wave w owns q-strip [16w,16w+16).
// Q pre-scaled by 0.125 (Q-GEMM EPI=3). V arrives pre-transposed as
// vt[b][h][d][n] -> Vt staged with b128 writes like K (no scalar transpose).
// All LDS tiles [64][64] bf16, XOR swizzle chunk^=row&7 both sides.
// LDS 32KB, 2 barriers/tile.
// ---------------------------------------------------------------------------
__device__ __forceinline__ int swz(int row, int chunk) {  // byte offset
  return row * 128 + ((chunk ^ (row & 7)) << 4);
}

__global__ __launch_bounds__(256) void attn_kernel(
    const u16* __restrict__ q, const u16* __restrict__ k,
    const u16* __restrict__ vt, u16* __restrict__ ctx) {
  __shared__ __align__(16) u16 Qs[4096];   // [qrow][d]    swz
  __shared__ __align__(16) u16 Ks[4096];   // [kcol][d]    swz
  __shared__ __align__(16) u16 Vt[4096];   // [d][kcol]    swz
  __shared__ __align__(16) u16 Ps[4096];   // [qrow][kcol] swz, wave-private
  const int tid  = threadIdx.x;
  const int lane = tid & 63;
  const int w    = tid >> 6;          // wave id -> q-strip base 16w
  const int fr   = lane & 15;
  const int g    = lane >> 4;
  const int qt = blockIdx.x, h = blockIdx.y, b = blockIdx.z;
  const size_t hbase = (size_t)b * SEQ * DIM + (size_t)h * HDM;
  const u16* vhd = vt + ((size_t)(b * NH + h) * HDM) * SEQ;  // [d][n]
  const int srow = tid >> 2;          // staging row 0..63
  const int sc   = (tid & 3) << 4;    // staging col 0,16,32,48
  const int sch  = sc >> 3;           // staging chunk base

  {  // stage Q tile
    const u16* qp = q + hbase + (size_t)(qt * 64 + srow) * DIM + sc;
    const uint4 q0 = *(const uint4*)qp;
    const uint4 q1 = *(const uint4*)(qp + 8);
    *(uint4*)((char*)Qs + swz(srow, sch))     = q0;
    *(uint4*)((char*)Qs + swz(srow, sch + 1)) = q1;
  }

  float m_[4] = {-INFINITY, -INFINITY, -INFINITY, -INFINITY};
  float l_[4] = {0.f, 0.f, 0.f, 0.f};
  f32x4 oacc[4];
#pragma unroll
  for (int f = 0; f < 4; ++f) oacc[f] = {0.f, 0.f, 0.f, 0.f};

  for (int kt = 0; kt < SEQ / 64; ++kt) {
    __syncthreads();  // prior tile's K/Vt reads complete
    {  // stage K [kcol][d] and Vt [d][kcol] — both straight b128 copies
      const u16* kp = k + hbase + (size_t)(kt * 64 + srow) * DIM + sc;
      const uint4 k0 = *(const uint4*)kp;
      const uint4 k1 = *(const uint4*)(kp + 8);
      *(uint4*)((char*)Ks + swz(srow, sch))     = k0;
      *(uint4*)((char*)Ks + swz(srow, sch + 1)) = k1;
      const u16* vp = vhd + (size_t)srow * SEQ + kt * 64 + sc;
      const uint4 v0 = *(const uint4*)vp;
      const uint4 v1 = *(const uint4*)(vp + 8);
      *(uint4*)((char*)Vt + swz(srow, sch))     = v0;
      *(uint4*)((char*)Vt + swz(srow, sch + 1)) = v1;
    }
    __syncthreads();  // K/Vt ready

    // ---- S-strip = Q.K^T ----
    f32x4 sacc[4];
#pragma unroll
    for (int f = 0; f < 4; ++f) sacc[f] = {0.f, 0.f, 0.f, 0.f};
    bf16x8 aq[2];
#pragma unroll
    for (int s = 0; s < 2; ++s)
      aq[s] = *(const bf16x8*)((char*)Qs + swz(w * 16 + fr, s * 4 + g));
#pragma unroll
    for (int f = 0; f < 4; ++f)
#pragma unroll
      for (int s = 0; s < 2; ++s) {
        const bf16x8 bk =
            *(const bf16x8*)((char*)Ks + swz(f * 16 + fr, s * 4 + g));
        sacc[f] = __builtin_amdgcn_mfma_f32_16x16x32_bf16(aq[s], bk, sacc[f],
                                                          0, 0, 0);
      }

    // ---- online softmax (scale pre-folded into Q) ----
    float corr[4];
#pragma unroll
    for (int r = 0; r < 4; ++r) {
      float rm = fmaxf(fmaxf(sacc[0][r], sacc[1][r]),
                       fmaxf(sacc[2][r], sacc[3][r]));
#pragma unroll
      for (int o = 8; o; o >>= 1) rm = fmaxf(rm, __shfl_xor(rm, o, 64));
      const float mnew = fmaxf(m_[r], rm);
      corr[r] = __expf(m_[r] - mnew);  // first tile: exp(-inf)=0
      float ps = 0.f;
#pragma unroll
      for (int f = 0; f < 4; ++f) {
        const float p = __expf(sacc[f][r] - mnew);
        sacc[f][r] = p;
        ps += p;
      }
#pragma unroll
      for (int o = 8; o; o >>= 1) ps += __shfl_xor(ps, o, 64);
      l_[r] = l_[r] * corr[r] + ps;
      m_[r] = mnew;
#pragma unroll
      for (int f = 0; f < 4; ++f) oacc[f][r] *= corr[r];
    }

    // ---- P -> LDS bf16 (wave-private strip; same-wave lgkmcnt ordering) ----
#pragma unroll
    for (int f = 0; f < 4; ++f)
#pragma unroll
      for (int r = 0; r < 4; ++r) {
        const int row = w * 16 + g * 4 + r;
        const int col = f * 16 + fr;
        *(u16*)((char*)Ps + ((row * 128 + col * 2) ^ ((row & 7) << 4))) =
            f2bf(sacc[f][r]);
      }

    // ---- ctx-strip += P.V ----
    bf16x8 ap[2];
#pragma unroll
    for (int s = 0; s < 2; ++s)
      ap[s] = *(const bf16x8*)((char*)Ps + swz(w * 16 + fr, s * 4 + g));
#pragma unroll
    for (int f = 0; f < 4; ++f)
#pragma unroll
      for (int s = 0; s < 2; ++s) {
        const bf16x8 bv =
            *(const bf16x8*)((char*)Vt + swz(f * 16 + fr, s * 4 + g));
        oacc[f] = __builtin_amdgcn_mfma_f32_16x16x32_bf16(ap[s], bv, oacc[f],
                                                          0, 0, 0);
      }
  }

  float inv[4];
#pragma unroll
  for (int r = 0; r < 4; ++r) inv[r] = 1.0f / l_[r];
#pragma unroll
  for (int f = 0; f < 4; ++f)
#pragma unroll
    for (int r = 0; r < 4; ++r) {
      const int qrow = qt * 64 + w * 16 + g * 4 + r;
      ctx[hbase + (size_t)qrow * DIM + f * 16 + fr] = f2bf(oacc[f][r] * inv[r]);
    }
}

// ---------------------------------------------------------------------------
// Orchestration. ws (u16 elems): Wt x6 (7.08M) | tokb (TD) | big (4*TD):
//   big = qb | kb | vt | (4th TD) — after attn, big is reused whole as the
//   MLP activation (NTOK x MLPD = 4*TD). Total 7.08M + 5*TD = 70.0M = 140MB.
// ---------------------------------------------------------------------------
extern "C" void kernel_launch(void* const* d_in, const int* in_sizes, int n_in,
                              void* d_out, int out_size, void* d_ws,
                              size_t ws_size, hipStream_t stream) {
  const float* x    = (const float*)d_in[0];
  const float* wq   = (const float*)d_in[1];
  const float* bq   = (const float*)d_in[2];
  const float* wk   = (const float*)d_in[3];
  const float* bk   = (const float*)d_in[4];
  const float* wv   = (const float*)d_in[5];
  const float* bv   = (const float*)d_in[6];
  const float* wo   = (const float*)d_in[7];
  const float* bo   = (const float*)d_in[8];
  const float* w1   = (const float*)d_in[9];
  const float* b1   = (const float*)d_in[10];
  const float* w2   = (const float*)d_in[11];
  const float* b2   = (const float*)d_in[12];
  const float* ln1g = (const float*)d_in[13];
  const float* ln1b = (const float*)d_in[14];
  const float* ln2g = (const float*)d_in[15];
  const float* ln2b = (const float*)d_in[16];
  float* out = (float*)d_out;

  const size_t TD = (size_t)NTOK * DIM;     // 12.58M
  const size_t S768 = (size_t)DIM * DIM;
  const size_t SMLP = (size_t)DIM * MLPD;
  u16* wtq  = (u16*)d_ws;
  u16* wtk  = wtq + S768;
  u16* wtv  = wtk + S768;
  u16* wto  = wtv + S768;
  u16* wt1  = wto + S768;                   // [MLPD][DIM]
  u16* wt2  = wt1 + SMLP;                   // [DIM][MLPD]
  u16* tokb = wt2 + SMLP;                   // h -> ctx -> h2
  u16* big  = tokb + TD;                    // 4*TD region
  u16* qb   = big;
  u16* kb   = big + TD;
  u16* vtb  = big + 2 * TD;                 // vt[b][h][d][n]

  const dim3 blk(256);
  wtrans_kernel<<<dim3(DIM / 64, DIM / 64), blk, 0, stream>>>(wq, wtq, DIM, DIM);
  wtrans_kernel<<<dim3(DIM / 64, DIM / 64), blk, 0, stream>>>(wk, wtk, DIM, DIM);
  wtrans_kernel<<<dim3(DIM / 64, DIM / 64), blk, 0, stream>>>(wv, wtv, DIM, DIM);
  wtrans_kernel<<<dim3(DIM / 64, DIM / 64), blk, 0, stream>>>(wo, wto, DIM, DIM);
  wtrans_kernel<<<dim3(MLPD / 64, DIM / 64), blk, 0, stream>>>(w1, wt1, DIM, MLPD);
  wtrans_kernel<<<dim3(DIM / 64, MLPD / 64), blk, 0, stream>>>(w2, wt2, MLPD, DIM);
  ln_kernel<<<dim3(NTOK / 4), blk, 0, stream>>>(x, ln1g, ln1b, tokb);
  const dim3 g768(DIM / 128, NTOK / 128);   // (6,128)
  mm_kernel<3><<<g768, blk, 0, stream>>>(tokb, wtq, bq, nullptr, qb, NTOK, DIM, DIM);
  mm_kernel<0><<<g768, blk, 0, stream>>>(tokb, wtk, bk, nullptr, kb, NTOK, DIM, DIM);
  mm_kernel<4><<<g768, blk, 0, stream>>>(tokb, wtv, bv, nullptr, vtb, NTOK, DIM, DIM);
  attn_kernel<<<dim3(SEQ / 64, NH, BS), blk, 0, stream>>>(qb, kb, vtb, tokb);
  mm_kernel<1><<<g768, blk, 0, stream>>>(tokb, wto, bo, x, out, NTOK, DIM, DIM);
  ln_kernel<<<dim3(NTOK / 4), blk, 0, stream>>>(out, ln2g, ln2b, tokb);
  mm_kernel<2><<<dim3(MLPD / 128, NTOK / 128), blk, 0, stream>>>(
      tokb, wt1, b1, nullptr, big, NTOK, DIM, MLPD);
  mm_kernel<1><<<g768, blk, 0, stream>>>(big, wt2, b2, out, out, NTOK, MLPD, DIM);
}

// Round 10
// 772.479 us; speedup vs baseline: 1.1165x; 1.0314x over previous
//
#include <hip/hip_runtime.h>
#include <hip/hip_bf16.h>
#include <math.h>

// Transformer block fwd: B=16, N=1024, D=768, H=12, HD=64, MLP=3072.
// Round 10: R8/R9 never ran (timeouts). Base: R7 PASSED 797us.
// Deltas queued: (1) attn T14 async-stage + K/V dbuf, 1 barrier/tile
// [audited 2x, race-traced]; (2) mm T1 bijective XCD swizzle (m204);
// (3) NEW: fused QKV GEMM (single launch, N=2304, block-uniform epilogue
// routing; numerics identical to 3 separate GEMMs).
// mm inner loop (m97-style) byte-identical to R5/R7-PASSED.

#define BS   16
#define SEQ  1024
#define DIM  768
#define NH   12
#define HDM  64
#define MLPD 3072
#define NTOK (BS * SEQ)          // 16384

typedef unsigned short u16;
typedef __attribute__((ext_vector_type(8))) short bf16x8;  // 8 bf16 (4 VGPRs)
typedef __attribute__((ext_vector_type(4))) float f32x4;   // MFMA acc

__device__ __forceinline__ float gelu_exact(float x) {
  return 0.5f * x * (1.0f + erff(x * 0.70710678118654752440f));
}
__device__ __forceinline__ u16 f2bf(float f) {  // HW convert (RTNE)
  __hip_bfloat16 h = __float2bfloat16(f);
  u16 r;
  __builtin_memcpy(&r, &h, 2);
  return r;
}
__device__ __forceinline__ u16 f2bf_sw(float f) {  // manual RTNE (cold paths)
  unsigned u = __float_as_uint(f);
  return (u16)((u + 0x7fffu + ((u >> 16) & 1u)) >> 16);
}

// ---------------------------------------------------------------------------
// Weight convert+transpose: fp32 W[K][N] -> bf16 Wt[N][K]. 64x64 LDS tile.
// ---------------------------------------------------------------------------
__global__ __launch_bounds__(256) void wtrans_kernel(
    const float* __restrict__ W, u16* __restrict__ Wt, int K, int N) {
  __shared__ u16 t[64][65];
  const int k0 = blockIdx.y << 6, n0 = blockIdx.x << 6;
  const int r  = threadIdx.x >> 2;            // 0..63
  const int c4 = (threadIdx.x & 3) << 4;      // 0,16,32,48
#pragma unroll
  for (int c = 0; c < 16; c += 4) {
    const float4 v = *(const float4*)(W + (size_t)(k0 + r) * N + n0 + c4 + c);
    t[r][c4 + c + 0] = f2bf_sw(v.x);
    t[r][c4 + c + 1] = f2bf_sw(v.y);
    t[r][c4 + c + 2] = f2bf_sw(v.z);
    t[r][c4 + c + 3] = f2bf_sw(v.w);
  }
  __syncthreads();
  unsigned wbuf[8];
#pragma unroll
  for (int p = 0; p < 8; ++p)
    wbuf[p] = (unsigned)t[c4 + 2 * p][r] | ((unsigned)t[c4 + 2 * p + 1][r] << 16);
  uint4* dst = (uint4*)(Wt + (size_t)(n0 + r) * K + k0 + c4);
  dst[0] = make_uint4(wbuf[0], wbuf[1], wbuf[2], wbuf[3]);
  dst[1] = make_uint4(wbuf[4], wbuf[5], wbuf[6], wbuf[7]);
}

// ---------------------------------------------------------------------------
// LayerNorm (fp32 in, bf16 out): one wave per token, 4 tokens per block.
// ---------------------------------------------------------------------------
__global__ __launch_bounds__(256) void ln_kernel(
    const float* __restrict__ x, const float* __restrict__ g,
    const float* __restrict__ b, u16* __restrict__ out) {
  const int lane = threadIdx.x & 63;
  const int wv   = threadIdx.x >> 6;
  const int tok  = (blockIdx.x << 2) + wv;
  const float4* xr = (const float4*)(x + (size_t)tok * DIM);
  float4 a0 = xr[lane], a1 = xr[lane + 64], a2 = xr[lane + 128];
  float s  = a0.x + a0.y + a0.z + a0.w + a1.x + a1.y + a1.z + a1.w
           + a2.x + a2.y + a2.z + a2.w;
  float s2 = a0.x*a0.x + a0.y*a0.y + a0.z*a0.z + a0.w*a0.w
           + a1.x*a1.x + a1.y*a1.y + a1.z*a1.z + a1.w*a1.w
           + a2.x*a2.x + a2.y*a2.y + a2.z*a2.z + a2.w*a2.w;
#pragma unroll
  for (int o = 32; o; o >>= 1) {
    s  += __shfl_xor(s,  o, 64);
    s2 += __shfl_xor(s2, o, 64);
  }
  const float mu   = s * (1.0f / DIM);
  const float rstd = rsqrtf(s2 * (1.0f / DIM) - mu * mu + 1e-6f);
  const float4* gp = (const float4*)g;
  const float4* bp = (const float4*)b;
  ushort4* op = (ushort4*)(out + (size_t)tok * DIM);
#define LN_EMIT(av, idx)                                                       \
  {                                                                            \
    const float4 gv = gp[idx]; const float4 bv = bp[idx]; ushort4 ov;          \
    ov.x = f2bf((av.x - mu) * rstd * gv.x + bv.x);                             \
    ov.y = f2bf((av.y - mu) * rstd * gv.y + bv.y);                             \
    ov.z = f2bf((av.z - mu) * rstd * gv.z + bv.z);                             \
    ov.w = f2bf((av.w - mu) * rstd * gv.w + bv.w);                             \
    op[idx] = ov;                                                              \
  }
  LN_EMIT(a0, lane);
  LN_EMIT(a1, lane + 64);
  LN_EMIT(a2, lane + 128);
#undef LN_EMIT
}

// ---------------------------------------------------------------------------
// Shared mm pieces (m97-style inner loop, R5/R7-PASSED) + T1 XCD swizzle.
// Fragment maps [m89/m91-verified + HW-PASS]:
//   A[l&15][(l>>4)*8+j]; B[(l>>4)*8+j][l&15]; C/D col=l&15, row=(l>>4)*4+reg.
// ---------------------------------------------------------------------------
__device__ __forceinline__ void stage128x32(const u16* gtile, int ldk,
                                            u16* lds, int tid) {
#pragma unroll
  for (int i = 0; i < 2; ++i) {
    const int b = i * 4096 + tid * 16;     // byte offset within tile
    const int row = b >> 6;
    const int chunk = (b >> 4) & 3;
    const u16* src = gtile + (size_t)row * ldk + chunk * 8;
    u16* dst = lds + ((i * 4096 + (tid >> 6) * 1024) >> 1);  // wave-uniform
    __builtin_amdgcn_global_load_lds((const void*)src, (void*)dst, 16, 0, 0);
  }
}

// T1 bijective XCD swizzle (m204). All grids here have nwg % 8 == 0.
__device__ __forceinline__ void xcd_swizzle(int& bx, int& by) {
  const int nwg  = gridDim.x * gridDim.y;
  const int orig = blockIdx.y * gridDim.x + blockIdx.x;
  const int q8 = nwg >> 3, r8 = nwg & 7;
  const int xcd = orig & 7, sub = orig >> 3;
  const int wgid = (xcd < r8 ? xcd * (q8 + 1)
                             : r8 * (q8 + 1) + (xcd - r8) * q8) + sub;
  bx = wgid % gridDim.x;
  by = wgid / gridDim.x;
}

// Inner K-loop: stages A/B 128x32 tiles (dbuf) and accumulates 4x4 fragments.
__device__ __forceinline__ void mm_core(const u16* Ab, const u16* Bb, int K,
                                        int tid, int wr, int wc, int fr,
                                        int kch, u16 (*As)[128 * 32],
                                        u16 (*Bs)[128 * 32], f32x4 acc[4][4]) {
  const int nkt = K >> 5;
  stage128x32(Ab, K, As[0], tid);
  stage128x32(Bb, K, Bs[0], tid);
  __syncthreads();
  int cur = 0;
  for (int kt = 0; kt < nkt; ++kt) {
    if (kt + 1 < nkt) {
      stage128x32(Ab + (kt + 1) * 32, K, As[cur ^ 1], tid);
      stage128x32(Bb + (kt + 1) * 32, K, Bs[cur ^ 1], tid);
    }
    bf16x8 af[4], bf[4];
#pragma unroll
    for (int f = 0; f < 4; ++f) {
      af[f] = *(const bf16x8*)&As[cur][(wr + (f << 4) + fr) * 32 + (kch << 3)];
      bf[f] = *(const bf16x8*)&Bs[cur][(wc + (f << 4) + fr) * 32 + (kch << 3)];
    }
#pragma unroll
    for (int i = 0; i < 4; ++i)
#pragma unroll
      for (int j = 0; j < 4; ++j)
        acc[i][j] = __builtin_amdgcn_mfma_f32_16x16x32_bf16(af[i], bf[j],
                                                            acc[i][j], 0, 0, 0);
    __syncthreads();
    cur ^= 1;
  }
}

// ---------------------------------------------------------------------------
// Generic mm: EPI 1 = bias+res(fp32)->fp32 (O-proj, MLP2);
//             EPI 2 = bias+GELU->bf16 (MLP1).
// ---------------------------------------------------------------------------
template <int EPI>
__global__ __launch_bounds__(256) void mm_kernel(
    const u16* __restrict__ A, const u16* __restrict__ Wt,
    const float* __restrict__ bias, const float* res, void* outp,
    int M, int K, int Nc) {
  __shared__ __align__(16) u16 As[2][128 * 32];
  __shared__ __align__(16) u16 Bs[2][128 * 32];
  const int tid  = threadIdx.x;
  const int lane = tid & 63;
  const int wid  = tid >> 6;
  const int wr   = (wid >> 1) << 6;
  const int wc   = (wid & 1) << 6;
  int bx, by;
  xcd_swizzle(bx, by);
  const int row0 = by << 7;
  const int col0 = bx << 7;
  const int fr   = lane & 15;
  const int kch  = lane >> 4;

  f32x4 acc[4][4];
#pragma unroll
  for (int i = 0; i < 4; ++i)
#pragma unroll
    for (int j = 0; j < 4; ++j) acc[i][j] = {0.f, 0.f, 0.f, 0.f};

  mm_core(A + (size_t)row0 * K, Wt + (size_t)col0 * K, K, tid, wr, wc, fr,
          kch, As, Bs, acc);

  float* outf = (float*)outp;
  u16*   outb = (u16*)outp;
#pragma unroll
  for (int jf = 0; jf < 4; ++jf) {
    const int c = col0 + wc + (jf << 4) + fr;
    const float bv = bias[c];
#pragma unroll
    for (int i = 0; i < 4; ++i) {
#pragma unroll
      for (int j = 0; j < 4; ++j) {
        const int r = row0 + wr + (i << 4) + ((lane >> 4) << 2) + j;
        float v = acc[i][jf][j] + bv;
        if (EPI == 1) v += res[(size_t)r * Nc + c];
        if (EPI == 2) v = gelu_exact(v);
        if (EPI == 1) outf[(size_t)r * Nc + c] = v;
        else          outb[(size_t)r * Nc + c] = f2bf(v);
      }
    }
  }
}

// ---------------------------------------------------------------------------
// Fused QKV GEMM: A=[NTOK][768] x Wt=[2304][768] (wtq|wtk|wtv contiguous).
// Epilogue routes by block-uniform sel = col0/768 (128 | 768 so each block
// lies wholly in one segment): Q -> *0.125 -> qb; K -> kb;
// V -> vt[b][h][d][n] scatter. Numerically identical to 3 separate GEMMs.
// ---------------------------------------------------------------------------
__global__ __launch_bounds__(256) void mmqkv_kernel(
    const u16* __restrict__ A, const u16* __restrict__ Wt,
    const float* __restrict__ bq, const float* __restrict__ bk,
    const float* __restrict__ bv, u16* __restrict__ qb,
    u16* __restrict__ kb, u16* __restrict__ vtb) {
  __shared__ __align__(16) u16 As[2][128 * 32];
  __shared__ __align__(16) u16 Bs[2][128 * 32];
  const int tid  = threadIdx.x;
  const int lane = tid & 63;
  const int wid  = tid >> 6;
  const int wr   = (wid >> 1) << 6;
  const int wc   = (wid & 1) << 6;
  int bx, by;
  xcd_swizzle(bx, by);
  const int row0 = by << 7;
  const int col0 = bx << 7;
  const int fr   = lane & 15;
  const int kch  = lane >> 4;

  f32x4 acc[4][4];
#pragma unroll
  for (int i = 0; i < 4; ++i)
#pragma unroll
    for (int j = 0; j < 4; ++j) acc[i][j] = {0.f, 0.f, 0.f, 0.f};

  mm_core(A + (size_t)row0 * DIM, Wt + (size_t)col0 * DIM, DIM, tid, wr, wc,
          fr, kch, As, Bs, acc);

  const int sel = col0 >= 1536 ? 2 : (col0 >= 768 ? 1 : 0);  // block-uniform
  const float* bias = sel == 0 ? bq : (sel == 1 ? bk : bv);
  const int cbase = col0 - sel * 768;
#pragma unroll
  for (int jf = 0; jf < 4; ++jf) {
    const int c = cbase + wc + (jf << 4) + fr;   // 0..767 within segment
    const float bvv = bias[c];
    if (sel == 2) {  // V scatter (same arithmetic as R7-PASSED EPI=4)
      const int hh = c >> 6, dd = c & 63;
#pragma unroll
      for (int i = 0; i < 4; ++i) {
        const int rbase = row0 + wr + (i << 4) + ((lane >> 4) << 2);
        const int bb = rbase >> 10, n0 = rbase & 1023;
        ushort4 o;
        o.x = f2bf(acc[i][jf][0] + bvv);
        o.y = f2bf(acc[i][jf][1] + bvv);
        o.z = f2bf(acc[i][jf][2] + bvv);
        o.w = f2bf(acc[i][jf][3] + bvv);
        *(ushort4*)(vtb + ((((size_t)bb * NH + hh) * HDM + dd) << 10) + n0) = o;
      }
    } else {
      u16* dst = sel == 0 ? qb : kb;
      const float sc = sel == 0 ? 0.125f : 1.0f;  // attn scale folded into Q
#pragma unroll
      for (int i = 0; i < 4; ++i)
#pragma unroll
        for (int j = 0; j < 4; ++j) {
          const int r = row0 + wr + (i << 4) + ((lane >> 4) << 2) + j;
          dst[(size_t)r * DIM + c] = f2bf((acc[i][jf][j] + bvv) * sc);
        }
    }
  }
}

// ---------------------------------------------------------------------------
// bf16-MFMA flash attention, T14 async-stage + K/V double-buffer.
// Block = (qtile 64 rows, head, batch); 4 waves, wave w owns q-strip
// [16w,16w+16). Per tile: issue kt+1 global loads BEFORE compute, LDS-write
// them AFTER compute into buf^1, ONE barrier per tile. Q pre-scaled 0.125;
// V pre-transposed (vt[b][h][d][n]). XOR swizzle chunk^=row&7 both sides.
// LDS 48KB -> 3 blocks/CU. Race audit (m152): writes at iter kt target
// buf[cur^1], last read at iter kt-1, fenced by kt-1's end barrier; Ps
// wave-private (same-wave lgkmcnt ordering).
// ---------------------------------------------------------------------------
__device__ __forceinline__ int swz(int row, int chunk) {  // byte offset
  return row * 128 + ((chunk ^ (row & 7)) << 4);
}

__global__ __launch_bounds__(256) void attn_kernel(
    const u16* __restrict__ q, const u16* __restrict__ k,
    const u16* __restrict__ vt, u16* __restrict__ ctx) {
  __shared__ __align__(16) u16 Qs[4096];      // [qrow][d]    swz
  __shared__ __align__(16) u16 Ks[2][4096];   // [kcol][d]    swz, dbuf
  __shared__ __align__(16) u16 Vt[2][4096];   // [d][kcol]    swz, dbuf
  __shared__ __align__(16) u16 Ps[4096];      // [qrow][kcol] swz, wave-private
  const int tid  = threadIdx.x;
  const int lane = tid & 63;
  const int w    = tid >> 6;          // wave id -> q-strip base 16w
  const int fr   = lane & 15;
  const int g    = lane >> 4;
  const int qt = blockIdx.x, h = blockIdx.y, b = blockIdx.z;
  const size_t hbase = (size_t)b * SEQ * DIM + (size_t)h * HDM;
  const u16* vhd = vt + ((size_t)(b * NH + h) * HDM) * SEQ;  // [d][n]
  const int srow = tid >> 2;          // staging row 0..63
  const int sc   = (tid & 3) << 4;    // staging col 0,16,32,48
  const int sch  = sc >> 3;           // staging chunk base

  {  // stage Q tile (read-only afterwards; covered by prologue barrier)
    const u16* qp = q + hbase + (size_t)(qt * 64 + srow) * DIM + sc;
    const uint4 q0 = *(const uint4*)qp;
    const uint4 q1 = *(const uint4*)(qp + 8);
    *(uint4*)((char*)Qs + swz(srow, sch))     = q0;
    *(uint4*)((char*)Qs + swz(srow, sch + 1)) = q1;
  }
  {  // prologue: stage K/V tile 0 into buf 0
    const u16* kp = k + hbase + (size_t)srow * DIM + sc;
    const u16* vp = vhd + (size_t)srow * SEQ + sc;
    const uint4 k0 = *(const uint4*)kp;
    const uint4 k1 = *(const uint4*)(kp + 8);
    const uint4 v0 = *(const uint4*)vp;
    const uint4 v1 = *(const uint4*)(vp + 8);
    *(uint4*)((char*)Ks[0] + swz(srow, sch))     = k0;
    *(uint4*)((char*)Ks[0] + swz(srow, sch + 1)) = k1;
    *(uint4*)((char*)Vt[0] + swz(srow, sch))     = v0;
    *(uint4*)((char*)Vt[0] + swz(srow, sch + 1)) = v1;
  }
  __syncthreads();

  float m_[4] = {-INFINITY, -INFINITY, -INFINITY, -INFINITY};
  float l_[4] = {0.f, 0.f, 0.f, 0.f};
  f32x4 oacc[4];
#pragma unroll
  for (int f = 0; f < 4; ++f) oacc[f] = {0.f, 0.f, 0.f, 0.f};

  int cur = 0;
  for (int kt = 0; kt < SEQ / 64; ++kt) {
    const bool pf = (kt + 1 < SEQ / 64);
    uint4 ka, kb2, va, vb2;
    if (pf) {  // T14: issue next tile's global loads BEFORE compute
      const u16* kp = k + hbase + (size_t)((kt + 1) * 64 + srow) * DIM + sc;
      const u16* vp = vhd + (size_t)srow * SEQ + (kt + 1) * 64 + sc;
      ka  = *(const uint4*)kp;
      kb2 = *(const uint4*)(kp + 8);
      va  = *(const uint4*)vp;
      vb2 = *(const uint4*)(vp + 8);
    }
    const u16* ksc = Ks[cur];
    const u16* vtc = Vt[cur];

    // ---- S-strip = Q.K^T ----
    f32x4 sacc[4];
#pragma unroll
    for (int f = 0; f < 4; ++f) sacc[f] = {0.f, 0.f, 0.f, 0.f};
    bf16x8 aq[2];
#pragma unroll
    for (int s = 0; s < 2; ++s)
      aq[s] = *(const bf16x8*)((char*)Qs + swz(w * 16 + fr, s * 4 + g));
#pragma unroll
    for (int f = 0; f < 4; ++f)
#pragma unroll
      for (int s = 0; s < 2; ++s) {
        const bf16x8 bk =
            *(const bf16x8*)((char*)ksc + swz(f * 16 + fr, s * 4 + g));
        sacc[f] = __builtin_amdgcn_mfma_f32_16x16x32_bf16(aq[s], bk, sacc[f],
                                                          0, 0, 0);
      }

    // ---- online softmax (scale pre-folded into Q) ----
    float corr[4];
#pragma unroll
    for (int r = 0; r < 4; ++r) {
      float rm = fmaxf(fmaxf(sacc[0][r], sacc[1][r]),
                       fmaxf(sacc[2][r], sacc[3][r]));
#pragma unroll
      for (int o = 8; o; o >>= 1) rm = fmaxf(rm, __shfl_xor(rm, o, 64));
      const float mnew = fmaxf(m_[r], rm);
      corr[r] = __expf(m_[r] - mnew);  // first tile: exp(-inf)=0
      float ps = 0.f;
#pragma unroll
      for (int f = 0; f < 4; ++f) {
        const float p = __expf(sacc[f][r] - mnew);
        sacc[f][r] = p;
        ps += p;
      }
#pragma unroll
      for (int o = 8; o; o >>= 1) ps += __shfl_xor(ps, o, 64);
      l_[r] = l_[r] * corr[r] + ps;
      m_[r] = mnew;
#pragma unroll
      for (int f = 0; f < 4; ++f) oacc[f][r] *= corr[r];
    }

    // ---- P -> LDS bf16 (wave-private strip) ----
#pragma unroll
    for (int f = 0; f < 4; ++f)
#pragma unroll
      for (int r = 0; r < 4; ++r) {
        const int row = w * 16 + g * 4 + r;
        const int col = f * 16 + fr;
        *(u16*)((char*)Ps + ((row * 128 + col * 2) ^ ((row & 7) << 4))) =
            f2bf(sacc[f][r]);
      }

    // ---- ctx-strip += P.V ----
    bf16x8 ap[2];
#pragma unroll
    for (int s = 0; s < 2; ++s)
      ap[s] = *(const bf16x8*)((char*)Ps + swz(w * 16 + fr, s * 4 + g));
#pragma unroll
    for (int f = 0; f < 4; ++f)
#pragma unroll
      for (int s = 0; s < 2; ++s) {
        const bf16x8 bv =
            *(const bf16x8*)((char*)vtc + swz(f * 16 + fr, s * 4 + g));
        oacc[f] = __builtin_amdgcn_mfma_f32_16x16x32_bf16(ap[s], bv, oacc[f],
                                                          0, 0, 0);
      }

    if (pf) {  // T14: LDS-write prefetched tile into buf^1, single barrier
      u16* ksn = Ks[cur ^ 1];
      u16* vtn = Vt[cur ^ 1];
      *(uint4*)((char*)ksn + swz(srow, sch))     = ka;
      *(uint4*)((char*)ksn + swz(srow, sch + 1)) = kb2;
      *(uint4*)((char*)vtn + swz(srow, sch))     = va;
      *(uint4*)((char*)vtn + swz(srow, sch + 1)) = vb2;
      __syncthreads();  // uniform (pf uniform); next iter reads buf^1
    }
    cur ^= 1;
  }

  float inv[4];
#pragma unroll
  for (int r = 0; r < 4; ++r) inv[r] = 1.0f / l_[r];
#pragma unroll
  for (int f = 0; f < 4; ++f)
#pragma unroll
    for (int r = 0; r < 4; ++r) {
      const int qrow = qt * 64 + w * 16 + g * 4 + r;
      ctx[hbase + (size_t)qrow * DIM + f * 16 + fr] = f2bf(oacc[f][r] * inv[r]);
    }
}

// ---------------------------------------------------------------------------
// Orchestration. ws (u16 elems): Wt x6 (7.08M; wtq|wtk|wtv contiguous =
// fused [2304][768]) | tokb (TD) | big (4*TD): qb | kb | vt | spare —
// after attn, big is reused whole as the MLP activation (NTOK x MLPD).
// Total 7.08M + 5*TD = 70.0M = 140MB.
// ---------------------------------------------------------------------------
extern "C" void kernel_launch(void* const* d_in, const int* in_sizes, int n_in,
                              void* d_out, int out_size, void* d_ws,
                              size_t ws_size, hipStream_t stream) {
  const float* x    = (const float*)d_in[0];
  const float* wq   = (const float*)d_in[1];
  const float* bq   = (const float*)d_in[2];
  const float* wk   = (const float*)d_in[3];
  const float* bk   = (const float*)d_in[4];
  const float* wv   = (const float*)d_in[5];
  const float* bv   = (const float*)d_in[6];
  const float* wo   = (const float*)d_in[7];
  const float* bo   = (const float*)d_in[8];
  const float* w1   = (const float*)d_in[9];
  const float* b1   = (const float*)d_in[10];
  const float* w2   = (const float*)d_in[11];
  const float* b2   = (const float*)d_in[12];
  const float* ln1g = (const float*)d_in[13];
  const float* ln1b = (const float*)d_in[14];
  const float* ln2g = (const float*)d_in[15];
  const float* ln2b = (const float*)d_in[16];
  float* out = (float*)d_out;

  const size_t TD = (size_t)NTOK * DIM;     // 12.58M
  const size_t S768 = (size_t)DIM * DIM;
  const size_t SMLP = (size_t)DIM * MLPD;
  u16* wtq  = (u16*)d_ws;                   // fused QKV Wt rows 0..767
  u16* wtk  = wtq + S768;                   // rows 768..1535
  u16* wtv  = wtk + S768;                   // rows 1536..2303
  u16* wto  = wtv + S768;
  u16* wt1  = wto + S768;                   // [MLPD][DIM]
  u16* wt2  = wt1 + SMLP;                   // [DIM][MLPD]
  u16* tokb = wt2 + SMLP;                   // h -> ctx -> h2
  u16* big  = tokb + TD;                    // 4*TD region
  u16* qb   = big;
  u16* kb   = big + TD;
  u16* vtb  = big + 2 * TD;                 // vt[b][h][d][n]

  const dim3 blk(256);
  wtrans_kernel<<<dim3(DIM / 64, DIM / 64), blk, 0, stream>>>(wq, wtq, DIM, DIM);
  wtrans_kernel<<<dim3(DIM / 64, DIM / 64), blk, 0, stream>>>(wk, wtk, DIM, DIM);
  wtrans_kernel<<<dim3(DIM / 64, DIM / 64), blk, 0, stream>>>(wv, wtv, DIM, DIM);
  wtrans_kernel<<<dim3(DIM / 64, DIM / 64), blk, 0, stream>>>(wo, wto, DIM, DIM);
  wtrans_kernel<<<dim3(MLPD / 64, DIM / 64), blk, 0, stream>>>(w1, wt1, DIM, MLPD);
  wtrans_kernel<<<dim3(DIM / 64, MLPD / 64), blk, 0, stream>>>(w2, wt2, MLPD, DIM);
  ln_kernel<<<dim3(NTOK / 4), blk, 0, stream>>>(x, ln1g, ln1b, tokb);
  // fused QKV: 1 launch, grid (2304/128, NTOK/128)
  mmqkv_kernel<<<dim3(18, NTOK / 128), blk, 0, stream>>>(
      tokb, wtq, bq, bk, bv, qb, kb, vtb);
  attn_kernel<<<dim3(SEQ / 64, NH, BS), blk, 0, stream>>>(qb, kb, vtb, tokb);
  const dim3 g768(DIM / 128, NTOK / 128);   // (6,128)
  mm_kernel<1><<<g768, blk, 0, stream>>>(tokb, wto, bo, x, out, NTOK, DIM, DIM);
  ln_kernel<<<dim3(NTOK / 4), blk, 0, stream>>>(out, ln2g, ln2b, tokb);
  mm_kernel<2><<<dim3(MLPD / 128, NTOK / 128), blk, 0, stream>>>(
      tokb, wt1, b1, nullptr, big, NTOK, DIM, MLPD);
  mm_kernel<1><<<g768, blk, 0, stream>>>(big, wt2, b2, out, out, NTOK, MLPD, DIM);
}

// Round 11
// 771.926 us; speedup vs baseline: 1.1173x; 1.0007x over previous
//
#include <hip/hip_runtime.h>
#include <hip/hip_bf16.h>
#include <math.h>

// Transformer block fwd: B=16, N=1024, D=768, H=12, HD=64, MLP=3072.
// Round 11. R10 PASSED 772us. Post-mortem: attn T14-with-LDS-dbuf REGRESSED
// (178.5 -> 192us; 48KB LDS cut occupancy 41.6->30.9%). Revised: T14 with
// REGISTER prefetch + single 32KB LDS set (R7's verified 2-barrier skeleton)
// + T5 setprio (m191 +4-7%) + T13 defer-max THR=8 (m214v23 +5%).
// mm side unchanged from R10-validated (fused QKV, XCD swizzle, m97 core).

#define BS   16
#define SEQ  1024
#define DIM  768
#define NH   12
#define HDM  64
#define MLPD 3072
#define NTOK (BS * SEQ)          // 16384

typedef unsigned short u16;
typedef __attribute__((ext_vector_type(8))) short bf16x8;  // 8 bf16 (4 VGPRs)
typedef __attribute__((ext_vector_type(4))) float f32x4;   // MFMA acc

__device__ __forceinline__ float gelu_exact(float x) {
  return 0.5f * x * (1.0f + erff(x * 0.70710678118654752440f));
}
__device__ __forceinline__ u16 f2bf(float f) {  // HW convert (RTNE)
  __hip_bfloat16 h = __float2bfloat16(f);
  u16 r;
  __builtin_memcpy(&r, &h, 2);
  return r;
}
__device__ __forceinline__ u16 f2bf_sw(float f) {  // manual RTNE (cold paths)
  unsigned u = __float_as_uint(f);
  return (u16)((u + 0x7fffu + ((u >> 16) & 1u)) >> 16);
}

// ---------------------------------------------------------------------------
// Weight convert+transpose: fp32 W[K][N] -> bf16 Wt[N][K]. 64x64 LDS tile.
// ---------------------------------------------------------------------------
__global__ __launch_bounds__(256) void wtrans_kernel(
    const float* __restrict__ W, u16* __restrict__ Wt, int K, int N) {
  __shared__ u16 t[64][65];
  const int k0 = blockIdx.y << 6, n0 = blockIdx.x << 6;
  const int r  = threadIdx.x >> 2;            // 0..63
  const int c4 = (threadIdx.x & 3) << 4;      // 0,16,32,48
#pragma unroll
  for (int c = 0; c < 16; c += 4) {
    const float4 v = *(const float4*)(W + (size_t)(k0 + r) * N + n0 + c4 + c);
    t[r][c4 + c + 0] = f2bf_sw(v.x);
    t[r][c4 + c + 1] = f2bf_sw(v.y);
    t[r][c4 + c + 2] = f2bf_sw(v.z);
    t[r][c4 + c + 3] = f2bf_sw(v.w);
  }
  __syncthreads();
  unsigned wbuf[8];
#pragma unroll
  for (int p = 0; p < 8; ++p)
    wbuf[p] = (unsigned)t[c4 + 2 * p][r] | ((unsigned)t[c4 + 2 * p + 1][r] << 16);
  uint4* dst = (uint4*)(Wt + (size_t)(n0 + r) * K + k0 + c4);
  dst[0] = make_uint4(wbuf[0], wbuf[1], wbuf[2], wbuf[3]);
  dst[1] = make_uint4(wbuf[4], wbuf[5], wbuf[6], wbuf[7]);
}

// ---------------------------------------------------------------------------
// LayerNorm (fp32 in, bf16 out): one wave per token, 4 tokens per block.
// ---------------------------------------------------------------------------
__global__ __launch_bounds__(256) void ln_kernel(
    const float* __restrict__ x, const float* __restrict__ g,
    const float* __restrict__ b, u16* __restrict__ out) {
  const int lane = threadIdx.x & 63;
  const int wv   = threadIdx.x >> 6;
  const int tok  = (blockIdx.x << 2) + wv;
  const float4* xr = (const float4*)(x + (size_t)tok * DIM);
  float4 a0 = xr[lane], a1 = xr[lane + 64], a2 = xr[lane + 128];
  float s  = a0.x + a0.y + a0.z + a0.w + a1.x + a1.y + a1.z + a1.w
           + a2.x + a2.y + a2.z + a2.w;
  float s2 = a0.x*a0.x + a0.y*a0.y + a0.z*a0.z + a0.w*a0.w
           + a1.x*a1.x + a1.y*a1.y + a1.z*a1.z + a1.w*a1.w
           + a2.x*a2.x + a2.y*a2.y + a2.z*a2.z + a2.w*a2.w;
#pragma unroll
  for (int o = 32; o; o >>= 1) {
    s  += __shfl_xor(s,  o, 64);
    s2 += __shfl_xor(s2, o, 64);
  }
  const float mu   = s * (1.0f / DIM);
  const float rstd = rsqrtf(s2 * (1.0f / DIM) - mu * mu + 1e-6f);
  const float4* gp = (const float4*)g;
  const float4* bp = (const float4*)b;
  ushort4* op = (ushort4*)(out + (size_t)tok * DIM);
#define LN_EMIT(av, idx)                                                       \
  {                                                                            \
    const float4 gv = gp[idx]; const float4 bv = bp[idx]; ushort4 ov;          \
    ov.x = f2bf((av.x - mu) * rstd * gv.x + bv.x);                             \
    ov.y = f2bf((av.y - mu) * rstd * gv.y + bv.y);                             \
    ov.z = f2bf((av.z - mu) * rstd * gv.z + bv.z);                             \
    ov.w = f2bf((av.w - mu) * rstd * gv.w + bv.w);                             \
    op[idx] = ov;                                                              \
  }
  LN_EMIT(a0, lane);
  LN_EMIT(a1, lane + 64);
  LN_EMIT(a2, lane + 128);
#undef LN_EMIT
}

// ---------------------------------------------------------------------------
// Shared mm pieces (m97-style inner loop, R5/R7/R10-PASSED) + T1 XCD swizzle.
// Fragment maps [m89/m91-verified + HW-PASS]:
//   A[l&15][(l>>4)*8+j]; B[(l>>4)*8+j][l&15]; C/D col=l&15, row=(l>>4)*4+reg.
// ---------------------------------------------------------------------------
__device__ __forceinline__ void stage128x32(const u16* gtile, int ldk,
                                            u16* lds, int tid) {
#pragma unroll
  for (int i = 0; i < 2; ++i) {
    const int b = i * 4096 + tid * 16;     // byte offset within tile
    const int row = b >> 6;
    const int chunk = (b >> 4) & 3;
    const u16* src = gtile + (size_t)row * ldk + chunk * 8;
    u16* dst = lds + ((i * 4096 + (tid >> 6) * 1024) >> 1);  // wave-uniform
    __builtin_amdgcn_global_load_lds((const void*)src, (void*)dst, 16, 0, 0);
  }
}

// T1 bijective XCD swizzle (m204). All grids here have nwg % 8 == 0.
__device__ __forceinline__ void xcd_swizzle(int& bx, int& by) {
  const int nwg  = gridDim.x * gridDim.y;
  const int orig = blockIdx.y * gridDim.x + blockIdx.x;
  const int q8 = nwg >> 3, r8 = nwg & 7;
  const int xcd = orig & 7, sub = orig >> 3;
  const int wgid = (xcd < r8 ? xcd * (q8 + 1)
                             : r8 * (q8 + 1) + (xcd - r8) * q8) + sub;
  bx = wgid % gridDim.x;
  by = wgid / gridDim.x;
}

// Inner K-loop: stages A/B 128x32 tiles (dbuf) and accumulates 4x4 fragments.
__device__ __forceinline__ void mm_core(const u16* Ab, const u16* Bb, int K,
                                        int tid, int wr, int wc, int fr,
                                        int kch, u16 (*As)[128 * 32],
                                        u16 (*Bs)[128 * 32], f32x4 acc[4][4]) {
  const int nkt = K >> 5;
  stage128x32(Ab, K, As[0], tid);
  stage128x32(Bb, K, Bs[0], tid);
  __syncthreads();
  int cur = 0;
  for (int kt = 0; kt < nkt; ++kt) {
    if (kt + 1 < nkt) {
      stage128x32(Ab + (kt + 1) * 32, K, As[cur ^ 1], tid);
      stage128x32(Bb + (kt + 1) * 32, K, Bs[cur ^ 1], tid);
    }
    bf16x8 af[4], bf[4];
#pragma unroll
    for (int f = 0; f < 4; ++f) {
      af[f] = *(const bf16x8*)&As[cur][(wr + (f << 4) + fr) * 32 + (kch << 3)];
      bf[f] = *(const bf16x8*)&Bs[cur][(wc + (f << 4) + fr) * 32 + (kch << 3)];
    }
#pragma unroll
    for (int i = 0; i < 4; ++i)
#pragma unroll
      for (int j = 0; j < 4; ++j)
        acc[i][j] = __builtin_amdgcn_mfma_f32_16x16x32_bf16(af[i], bf[j],
                                                            acc[i][j], 0, 0, 0);
    __syncthreads();
    cur ^= 1;
  }
}

// ---------------------------------------------------------------------------
// Generic mm: EPI 1 = bias+res(fp32)->fp32 (O-proj, MLP2);
//             EPI 2 = bias+GELU->bf16 (MLP1).
// ---------------------------------------------------------------------------
template <int EPI>
__global__ __launch_bounds__(256) void mm_kernel(
    const u16* __restrict__ A, const u16* __restrict__ Wt,
    const float* __restrict__ bias, const float* res, void* outp,
    int M, int K, int Nc) {
  __shared__ __align__(16) u16 As[2][128 * 32];
  __shared__ __align__(16) u16 Bs[2][128 * 32];
  const int tid  = threadIdx.x;
  const int lane = tid & 63;
  const int wid  = tid >> 6;
  const int wr   = (wid >> 1) << 6;
  const int wc   = (wid & 1) << 6;
  int bx, by;
  xcd_swizzle(bx, by);
  const int row0 = by << 7;
  const int col0 = bx << 7;
  const int fr   = lane & 15;
  const int kch  = lane >> 4;

  f32x4 acc[4][4];
#pragma unroll
  for (int i = 0; i < 4; ++i)
#pragma unroll
    for (int j = 0; j < 4; ++j) acc[i][j] = {0.f, 0.f, 0.f, 0.f};

  mm_core(A + (size_t)row0 * K, Wt + (size_t)col0 * K, K, tid, wr, wc, fr,
          kch, As, Bs, acc);

  float* outf = (float*)outp;
  u16*   outb = (u16*)outp;
#pragma unroll
  for (int jf = 0; jf < 4; ++jf) {
    const int c = col0 + wc + (jf << 4) + fr;
    const float bv = bias[c];
#pragma unroll
    for (int i = 0; i < 4; ++i) {
#pragma unroll
      for (int j = 0; j < 4; ++j) {
        const int r = row0 + wr + (i << 4) + ((lane >> 4) << 2) + j;
        float v = acc[i][jf][j] + bv;
        if (EPI == 1) v += res[(size_t)r * Nc + c];
        if (EPI == 2) v = gelu_exact(v);
        if (EPI == 1) outf[(size_t)r * Nc + c] = v;
        else          outb[(size_t)r * Nc + c] = f2bf(v);
      }
    }
  }
}

// ---------------------------------------------------------------------------
// Fused QKV GEMM (R10-PASSED): A=[NTOK][768] x Wt=[2304][768].
// Block-uniform sel = col0/768: Q -> *0.125 -> qb; K -> kb;
// V -> vt[b][h][d][n] scatter.
// ---------------------------------------------------------------------------
__global__ __launch_bounds__(256) void mmqkv_kernel(
    const u16* __restrict__ A, const u16* __restrict__ Wt,
    const float* __restrict__ bq, const float* __restrict__ bk,
    const float* __restrict__ bv, u16* __restrict__ qb,
    u16* __restrict__ kb, u16* __restrict__ vtb) {
  __shared__ __align__(16) u16 As[2][128 * 32];
  __shared__ __align__(16) u16 Bs[2][128 * 32];
  const int tid  = threadIdx.x;
  const int lane = tid & 63;
  const int wid  = tid >> 6;
  const int wr   = (wid >> 1) << 6;
  const int wc   = (wid & 1) << 6;
  int bx, by;
  xcd_swizzle(bx, by);
  const int row0 = by << 7;
  const int col0 = bx << 7;
  const int fr   = lane & 15;
  const int kch  = lane >> 4;

  f32x4 acc[4][4];
#pragma unroll
  for (int i = 0; i < 4; ++i)
#pragma unroll
    for (int j = 0; j < 4; ++j) acc[i][j] = {0.f, 0.f, 0.f, 0.f};

  mm_core(A + (size_t)row0 * DIM, Wt + (size_t)col0 * DIM, DIM, tid, wr, wc,
          fr, kch, As, Bs, acc);

  const int sel = col0 >= 1536 ? 2 : (col0 >= 768 ? 1 : 0);  // block-uniform
  const float* bias = sel == 0 ? bq : (sel == 1 ? bk : bv);
  const int cbase = col0 - sel * 768;
#pragma unroll
  for (int jf = 0; jf < 4; ++jf) {
    const int c = cbase + wc + (jf << 4) + fr;   // 0..767 within segment
    const float bvv = bias[c];
    if (sel == 2) {  // V scatter
      const int hh = c >> 6, dd = c & 63;
#pragma unroll
      for (int i = 0; i < 4; ++i) {
        const int rbase = row0 + wr + (i << 4) + ((lane >> 4) << 2);
        const int bb = rbase >> 10, n0 = rbase & 1023;
        ushort4 o;
        o.x = f2bf(acc[i][jf][0] + bvv);
        o.y = f2bf(acc[i][jf][1] + bvv);
        o.z = f2bf(acc[i][jf][2] + bvv);
        o.w = f2bf(acc[i][jf][3] + bvv);
        *(ushort4*)(vtb + ((((size_t)bb * NH + hh) * HDM + dd) << 10) + n0) = o;
      }
    } else {
      u16* dst = sel == 0 ? qb : kb;
      const float sc = sel == 0 ? 0.125f : 1.0f;  // attn scale folded into Q
#pragma unroll
      for (int i = 0; i < 4; ++i)
#pragma unroll
        for (int j = 0; j < 4; ++j) {
          const int r = row0 + wr + (i << 4) + ((lane >> 4) << 2) + j;
          dst[(size_t)r * DIM + c] = f2bf((acc[i][jf][j] + bvv) * sc);
        }
    }
  }
}

// ---------------------------------------------------------------------------
// bf16-MFMA flash attention. R7's verified 2-barrier single-buffer skeleton
// (32KB LDS) + T14 REGISTER prefetch (issue kt+1 loads pre-compute, LDS-write
// post-barrier; +16 VGPR instead of +16KB LDS — fixes R10's occupancy loss)
// + T5 setprio around MFMA clusters + T13 defer-max (THR=8, wave-uniform).
// ---------------------------------------------------------------------------
__device__ __forceinline__ int swz(int row, int chunk) {  // byte offset
  return row * 128 + ((chunk ^ (row & 7)) << 4);
}

__global__ __launch_bounds__(256) void attn_kernel(
    const u16* __restrict__ q, const u16* __restrict__ k,
    const u16* __restrict__ vt, u16* __restrict__ ctx) {
  __shared__ __align__(16) u16 Qs[4096];   // [qrow][d]    swz
  __shared__ __align__(16) u16 Ks[4096];   // [kcol][d]    swz
  __shared__ __align__(16) u16 Vt[4096];   // [d][kcol]    swz
  __shared__ __align__(16) u16 Ps[4096];   // [qrow][kcol] swz, wave-private
  const int tid  = threadIdx.x;
  const int lane = tid & 63;
  const int w    = tid >> 6;          // wave id -> q-strip base 16w
  const int fr   = lane & 15;
  const int g    = lane >> 4;
  const int qt = blockIdx.x, h = blockIdx.y, b = blockIdx.z;
  const size_t hbase = (size_t)b * SEQ * DIM + (size_t)h * HDM;
  const u16* vhd = vt + ((size_t)(b * NH + h) * HDM) * SEQ;  // [d][n]
  const int srow = tid >> 2;          // staging row 0..63
  const int sc   = (tid & 3) << 4;    // staging col 0,16,32,48
  const int sch  = sc >> 3;           // staging chunk base

  {  // stage Q tile + K/V tile 0
    const u16* qp = q + hbase + (size_t)(qt * 64 + srow) * DIM + sc;
    const uint4 q0 = *(const uint4*)qp;
    const uint4 q1 = *(const uint4*)(qp + 8);
    *(uint4*)((char*)Qs + swz(srow, sch))     = q0;
    *(uint4*)((char*)Qs + swz(srow, sch + 1)) = q1;
    const u16* kp = k + hbase + (size_t)srow * DIM + sc;
    const u16* vp = vhd + (size_t)srow * SEQ + sc;
    const uint4 k0 = *(const uint4*)kp;
    const uint4 k1 = *(const uint4*)(kp + 8);
    const uint4 v0 = *(const uint4*)vp;
    const uint4 v1 = *(const uint4*)(vp + 8);
    *(uint4*)((char*)Ks + swz(srow, sch))     = k0;
    *(uint4*)((char*)Ks + swz(srow, sch + 1)) = k1;
    *(uint4*)((char*)Vt + swz(srow, sch))     = v0;
    *(uint4*)((char*)Vt + swz(srow, sch + 1)) = v1;
  }
  __syncthreads();

  float m_[4] = {-INFINITY, -INFINITY, -INFINITY, -INFINITY};
  float l_[4] = {0.f, 0.f, 0.f, 0.f};
  f32x4 oacc[4];
#pragma unroll
  for (int f = 0; f < 4; ++f) oacc[f] = {0.f, 0.f, 0.f, 0.f};

  for (int kt = 0; kt < SEQ / 64; ++kt) {
    const bool pf = (kt + 1 < SEQ / 64);
    uint4 ka, kb2, va, vb2;
    if (pf) {  // T14: issue next tile's loads now; consumed after compute.
      const u16* kp = k + hbase + (size_t)((kt + 1) * 64 + srow) * DIM + sc;
      const u16* vp = vhd + (size_t)srow * SEQ + (kt + 1) * 64 + sc;
      ka  = *(const uint4*)kp;
      kb2 = *(const uint4*)(kp + 8);
      va  = *(const uint4*)vp;
      vb2 = *(const uint4*)(vp + 8);
    }

    // ---- S-strip = Q.K^T ----
    f32x4 sacc[4];
#pragma unroll
    for (int f = 0; f < 4; ++f) sacc[f] = {0.f, 0.f, 0.f, 0.f};
    bf16x8 aq[2];
#pragma unroll
    for (int s = 0; s < 2; ++s)
      aq[s] = *(const bf16x8*)((char*)Qs + swz(w * 16 + fr, s * 4 + g));
    __builtin_amdgcn_s_setprio(1);  // T5
#pragma unroll
    for (int f = 0; f < 4; ++f)
#pragma unroll
      for (int s = 0; s < 2; ++s) {
        const bf16x8 bk =
            *(const bf16x8*)((char*)Ks + swz(f * 16 + fr, s * 4 + g));
        sacc[f] = __builtin_amdgcn_mfma_f32_16x16x32_bf16(aq[s], bk, sacc[f],
                                                          0, 0, 0);
      }
    __builtin_amdgcn_s_setprio(0);

    // ---- online softmax with T13 defer-max (THR=8) ----
    float rm[4];
#pragma unroll
    for (int r = 0; r < 4; ++r) {
      float t = fmaxf(fmaxf(sacc[0][r], sacc[1][r]),
                      fmaxf(sacc[2][r], sacc[3][r]));
#pragma unroll
      for (int o = 8; o; o >>= 1) t = fmaxf(t, __shfl_xor(t, o, 64));
      rm[r] = t;
    }
    const bool ok = (rm[0] <= m_[0] + 8.f) && (rm[1] <= m_[1] + 8.f) &&
                    (rm[2] <= m_[2] + 8.f) && (rm[3] <= m_[3] + 8.f);
    if (__all(ok)) {  // fast path: keep m, no O/l rescale; P bounded by e^8
#pragma unroll
      for (int r = 0; r < 4; ++r) {
        float ps = 0.f;
#pragma unroll
        for (int f = 0; f < 4; ++f) {
          const float p = __expf(sacc[f][r] - m_[r]);
          sacc[f][r] = p;
          ps += p;
        }
#pragma unroll
        for (int o = 8; o; o >>= 1) ps += __shfl_xor(ps, o, 64);
        l_[r] += ps;
      }
    } else {  // slow path (first tile lands here: m=-inf)
#pragma unroll
      for (int r = 0; r < 4; ++r) {
        const float mnew = fmaxf(m_[r], rm[r]);
        const float corr = __expf(m_[r] - mnew);
        float ps = 0.f;
#pragma unroll
        for (int f = 0; f < 4; ++f) {
          const float p = __expf(sacc[f][r] - mnew);
          sacc[f][r] = p;
          ps += p;
        }
#pragma unroll
        for (int o = 8; o; o >>= 1) ps += __shfl_xor(ps, o, 64);
        l_[r] = l_[r] * corr + ps;
        m_[r] = mnew;
#pragma unroll
        for (int f = 0; f < 4; ++f) oacc[f][r] *= corr;
      }
    }

    // ---- P -> LDS bf16 (wave-private strip; same-wave lgkmcnt ordering) ----
#pragma unroll
    for (int f = 0; f < 4; ++f)
#pragma unroll
      for (int r = 0; r < 4; ++r) {
        const int row = w * 16 + g * 4 + r;
        const int col = f * 16 + fr;
        *(u16*)((char*)Ps + ((row * 128 + col * 2) ^ ((row & 7) << 4))) =
            f2bf(sacc[f][r]);
      }

    // ---- ctx-strip += P.V ----
    bf16x8 ap[2];
#pragma unroll
    for (int s = 0; s < 2; ++s)
      ap[s] = *(const bf16x8*)((char*)Ps + swz(w * 16 + fr, s * 4 + g));
    __builtin_amdgcn_s_setprio(1);  // T5
#pragma unroll
    for (int f = 0; f < 4; ++f)
#pragma unroll
      for (int s = 0; s < 2; ++s) {
        const bf16x8 bv =
            *(const bf16x8*)((char*)Vt + swz(f * 16 + fr, s * 4 + g));
        oacc[f] = __builtin_amdgcn_mfma_f32_16x16x32_bf16(ap[s], bv, oacc[f],
                                                          0, 0, 0);
      }
    __builtin_amdgcn_s_setprio(0);

    __syncthreads();  // all reads of Ks/Vt (tile kt) complete
    if (pf) {         // write prefetched tile kt+1 into the same buffers
      *(uint4*)((char*)Ks + swz(srow, sch))     = ka;
      *(uint4*)((char*)Ks + swz(srow, sch + 1)) = kb2;
      *(uint4*)((char*)Vt + swz(srow, sch))     = va;
      *(uint4*)((char*)Vt + swz(srow, sch + 1)) = vb2;
      __syncthreads();  // tile kt+1 visible to all waves
    }
  }

  float inv[4];
#pragma unroll
  for (int r = 0; r < 4; ++r) inv[r] = 1.0f / l_[r];
#pragma unroll
  for (int f = 0; f < 4; ++f)
#pragma unroll
    for (int r = 0; r < 4; ++r) {
      const int qrow = qt * 64 + w * 16 + g * 4 + r;
      ctx[hbase + (size_t)qrow * DIM + f * 16 + fr] = f2bf(oacc[f][r] * inv[r]);
    }
}

// ---------------------------------------------------------------------------
// Orchestration. ws (u16 elems): Wt x6 (7.08M; wtq|wtk|wtv contiguous =
// fused [2304][768]) | tokb (TD) | big (4*TD): qb | kb | vt | spare —
// after attn, big is reused whole as the MLP activation (NTOK x MLPD).
// Total 7.08M + 5*TD = 70.0M = 140MB.
// ---------------------------------------------------------------------------
extern "C" void kernel_launch(void* const* d_in, const int* in_sizes, int n_in,
                              void* d_out, int out_size, void* d_ws,
                              size_t ws_size, hipStream_t stream) {
  const float* x    = (const float*)d_in[0];
  const float* wq   = (const float*)d_in[1];
  const float* bq   = (const float*)d_in[2];
  const float* wk   = (const float*)d_in[3];
  const float* bk   = (const float*)d_in[4];
  const float* wv   = (const float*)d_in[5];
  const float* bv   = (const float*)d_in[6];
  const float* wo   = (const float*)d_in[7];
  const float* bo   = (const float*)d_in[8];
  const float* w1   = (const float*)d_in[9];
  const float* b1   = (const float*)d_in[10];
  const float* w2   = (const float*)d_in[11];
  const float* b2   = (const float*)d_in[12];
  const float* ln1g = (const float*)d_in[13];
  const float* ln1b = (const float*)d_in[14];
  const float* ln2g = (const float*)d_in[15];
  const float* ln2b = (const float*)d_in[16];
  float* out = (float*)d_out;

  const size_t TD = (size_t)NTOK * DIM;     // 12.58M
  const size_t S768 = (size_t)DIM * DIM;
  const size_t SMLP = (size_t)DIM * MLPD;
  u16* wtq  = (u16*)d_ws;                   // fused QKV Wt rows 0..767
  u16* wtk  = wtq + S768;                   // rows 768..1535
  u16* wtv  = wtk + S768;                   // rows 1536..2303
  u16* wto  = wtv + S768;
  u16* wt1  = wto + S768;                   // [MLPD][DIM]
  u16* wt2  = wt1 + SMLP;                   // [DIM][MLPD]
  u16* tokb = wt2 + SMLP;                   // h -> ctx -> h2
  u16* big  = tokb + TD;                    // 4*TD region
  u16* qb   = big;
  u16* kb   = big + TD;
  u16* vtb  = big + 2 * TD;                 // vt[b][h][d][n]

  const dim3 blk(256);
  wtrans_kernel<<<dim3(DIM / 64, DIM / 64), blk, 0, stream>>>(wq, wtq, DIM, DIM);
  wtrans_kernel<<<dim3(DIM / 64, DIM / 64), blk, 0, stream>>>(wk, wtk, DIM, DIM);
  wtrans_kernel<<<dim3(DIM / 64, DIM / 64), blk, 0, stream>>>(wv, wtv, DIM, DIM);
  wtrans_kernel<<<dim3(DIM / 64, DIM / 64), blk, 0, stream>>>(wo, wto, DIM, DIM);
  wtrans_kernel<<<dim3(MLPD / 64, DIM / 64), blk, 0, stream>>>(w1, wt1, DIM, MLPD);
  wtrans_kernel<<<dim3(DIM / 64, MLPD / 64), blk, 0, stream>>>(w2, wt2, MLPD, DIM);
  ln_kernel<<<dim3(NTOK / 4), blk, 0, stream>>>(x, ln1g, ln1b, tokb);
  // fused QKV: 1 launch, grid (2304/128, NTOK/128)
  mmqkv_kernel<<<dim3(18, NTOK / 128), blk, 0, stream>>>(
      tokb, wtq, bq, bk, bv, qb, kb, vtb);
  attn_kernel<<<dim3(SEQ / 64, NH, BS), blk, 0, stream>>>(qb, kb, vtb, tokb);
  const dim3 g768(DIM / 128, NTOK / 128);   // (6,128)
  mm_kernel<1><<<g768, blk, 0, stream>>>(tokb, wto, bo, x, out, NTOK, DIM, DIM);
  ln_kernel<<<dim3(NTOK / 4), blk, 0, stream>>>(out, ln2g, ln2b, tokb);
  mm_kernel<2><<<dim3(MLPD / 128, NTOK / 128), blk, 0, stream>>>(
      tokb, wt1, b1, nullptr, big, NTOK, DIM, MLPD);
  mm_kernel<1><<<g768, blk, 0, stream>>>(big, wt2, b2, out, out, NTOK, MLPD, DIM);
}